// Round 2
// 342.854 us; speedup vs baseline: 1.2925x; 1.2925x over previous
//
#include <hip/hip_runtime.h>
#include <math.h>

#define NBINS 18
#define NB 2
#define NC 16
#define FP 30
#define FA 50
#define NS 20
#define NT 1024
#define TS 128              // t per staging chunk
#define NCH (NT / TS)       // 8
#define PGSZ 15             // p's per block
#define NTHR 384
#define BSTR 136            // shorts per B row (128 + 8 pad) = 272 B, 16B-aligned
#define BINSTR 136          // bytes per bins row (128 + 8 pad)
#define ACCW 52

#define BIN_OFF (2 * 64 * BSTR * 2)       // 34816
#define CUT_OFF (BIN_OFF + PGSZ * BINSTR) // 36856
#define SMEM_B (CUT_OFF + 19 * 4)         // 36932

typedef __attribute__((ext_vector_type(8))) short bf16x8;
typedef __attribute__((ext_vector_type(4))) float f32x4;

__device__ inline float u2f(unsigned int u) { return __builtin_bit_cast(float, u); }
__device__ inline unsigned short f2bf(float x) {
    unsigned int u = __builtin_bit_cast(unsigned int, x);
    unsigned int r = (u + 0x7FFFu + ((u >> 16) & 1u)) >> 16;   // RNE
    return (unsigned short)r;
}

// Exact bucketize: b = #{j in 1..17 : cuts[j] < v}. Arithmetic estimate is
// within +/-1 of truth (est err ~1e-6 bins << bin width), then fixup against
// the LDS cutoff table makes it bit-exact vs the compare-count.
__device__ __forceinline__ int bin_of(float v, const float* cl) {
    int b0 = __float2int_rd(fmaf(v, 2.86478897565f, 9.0f));   // (v+pi)*18/(2pi)
    b0 = b0 < 0 ? 0 : (b0 > 17 ? 17 : b0);
    const float lo = cl[b0];
    const float hi = cl[b0 + 1];
    return b0 + (int)((b0 < 17) & (hi < v)) - (int)((b0 > 0) & !(lo < v));
}

template <bool DIRECT>
__global__ __launch_bounds__(NTHR) void mi_mfma(const float* __restrict__ pha,
                                                const float* __restrict__ amp,
                                                const float* __restrict__ cut,
                                                float* __restrict__ outp) {
    __shared__ __align__(16) char smem[SMEM_B];
    short* Bh = (short*)smem;
    float* accs = (float*)smem;           // epilogue reuse
    float* cl = (float*)(smem + CUT_OFF); // 19 cutoffs for bin fixup

    // block decode: pairs (g, g+8) share bcs's amp slice on the same XCD
    const int g   = blockIdx.x;
    const int pg  = (g >> 3) & 1;
    const int bcs = (g >> 4) * 8 + (g & 7);
    const int s   = bcs % NS;
    const int bc  = bcs / NS;
    const int p0  = pg * PGSZ;

    const int tid  = threadIdx.x;
    const int lane = tid & 63;
    const int w    = tid >> 6;            // 0..5
    const int l16  = lane & 15;
    const int quad = lane >> 4;

    if (tid < 19) cl[tid] = cut[tid];     // visible after first barrier

    // per-lane one-hot row params: rows w*48 + mt*16 + l16
    int pm[3]; unsigned kx[3];
    #pragma unroll
    for (int mt = 0; mt < 3; ++mt) {
        const int row = w * 48 + mt * 16 + l16;
        const int valid = row < PGSZ * NBINS;
        const int p = valid ? (row / NBINS) : (PGSZ - 1);
        const int kb = valid ? (row - p * NBINS) : 31;   // 31: never matches (bins<=17), no byte-carry
        pm[mt] = p;
        kx[mt] = (unsigned)kb * 0x01010101u;
    }

    // count column (a=50): hi=1.0 bf16, lo=0 — written once, never overwritten
    for (int t = tid; t < TS; t += NTHR) {
        Bh[FA * BSTR + t] = (short)0x3F80;
        Bh[64 * BSTR + FA * BSTR + t] = 0;
    }

    f32x4 acc[3][4];
    #pragma unroll
    for (int mt = 0; mt < 3; ++mt)
        #pragma unroll
        for (int nt = 0; nt < 4; ++nt) acc[mt][nt] = (f32x4){0.f, 0.f, 0.f, 0.f};

    const size_t phabase0 = ((size_t)(bc * FP + p0) * NS + s) * NT;
    const size_t ampbase0 = ((size_t)bc * FA * NS + s) * NT;

    // ---- T14 register prefetch: global loads for chunk ch issued during the
    // previous chunk's MFMA phase; converted+written to LDS next staging phase.
    float4 ph_pf[2];   // 480 float4 of pha: r=0 full, r=1 tid<96
    float4 am_pf[5];   // 1600 float4 of amp: r=0..3 full, r=4 tid<64

    auto LOAD = [&](int ch) {
        const float* pb = pha + phabase0 + ch * TS;
        #pragma unroll
        for (int r = 0; r < 2; ++r) {
            const int i = tid + r * NTHR;
            if (i < PGSZ * (TS / 4)) {
                const int p = i >> 5, tq = i & 31;
                ph_pf[r] = *(const float4*)(pb + (size_t)p * (NS * NT) + tq * 4);
            }
        }
        const float* ab = amp + ampbase0 + ch * TS;
        #pragma unroll
        for (int r = 0; r < 5; ++r) {
            const int i = tid + r * NTHR;
            if (i < FA * (TS / 4)) {
                const int a_ = i >> 5, tq = i & 31;
                am_pf[r] = *(const float4*)(ab + (size_t)a_ * (NS * NT) + tq * 4);
            }
        }
    };

    LOAD(0);

    for (int ch = 0; ch < NCH; ++ch) {
        __syncthreads();   // prev chunk's MFMA reads done; prefetched loads drained here
        // ---- stage bins: 480 float4, packed u32 writes (dword-aligned, conflict-free) ----
        #pragma unroll
        for (int r = 0; r < 2; ++r) {
            const int i = tid + r * NTHR;
            if (i < PGSZ * (TS / 4)) {
                const int p = i >> 5, tq = i & 31;
                const float4 v4 = ph_pf[r];
                const unsigned pk = (unsigned)bin_of(v4.x, cl)
                                  | ((unsigned)bin_of(v4.y, cl) << 8)
                                  | ((unsigned)bin_of(v4.z, cl) << 16)
                                  | ((unsigned)bin_of(v4.w, cl) << 24);
                *(unsigned*)(smem + BIN_OFF + p * BINSTR + tq * 4) = pk;
            }
        }
        // ---- stage amp hi/lo bf16 planes from prefetched regs ----
        #pragma unroll
        for (int r = 0; r < 5; ++r) {
            const int i = tid + r * NTHR;
            if (i < FA * (TS / 4)) {
                const int a_ = i >> 5, tq = i & 31;
                const float4 v4 = am_pf[r];
                const unsigned short h0 = f2bf(v4.x), h1 = f2bf(v4.y);
                const unsigned short h2 = f2bf(v4.z), h3 = f2bf(v4.w);
                const unsigned short q0 = f2bf(v4.x - u2f((unsigned)h0 << 16));
                const unsigned short q1 = f2bf(v4.y - u2f((unsigned)h1 << 16));
                const unsigned short q2 = f2bf(v4.z - u2f((unsigned)h2 << 16));
                const unsigned short q3 = f2bf(v4.w - u2f((unsigned)h3 << 16));
                short* dst = Bh + a_ * BSTR + tq * 4;
                uint2 hv; hv.x = (unsigned)h0 | ((unsigned)h1 << 16); hv.y = (unsigned)h2 | ((unsigned)h3 << 16);
                uint2 lv; lv.x = (unsigned)q0 | ((unsigned)q1 << 16); lv.y = (unsigned)q2 | ((unsigned)q3 << 16);
                *(uint2*)dst = hv;
                *(uint2*)(dst + 64 * BSTR) = lv;
            }
        }
        __syncthreads();
        if (ch + 1 < NCH) LOAD(ch + 1);   // latency hides under MFMA phase below
        // ---- MFMA phase: 4 K-steps of 32 ----
        #pragma unroll
        for (int ks = 0; ks < 4; ++ks) {
            // A fragments: one-hot built in registers from bins (broadcast b64 reads)
            bf16x8 af[3];
            #pragma unroll
            for (int mt = 0; mt < 3; ++mt) {
                const uint2 d = *(const uint2*)(smem + BIN_OFF + pm[mt] * BINSTR + ks * 32 + quad * 8);
                const unsigned x0 = d.x ^ kx[mt];
                const unsigned x1 = d.y ^ kx[mt];
                const unsigned f0 = ~(x0 + 0x7F7F7F7Fu) & 0x80808080u;  // exact: bytes <= 31
                const unsigned f1 = ~(x1 + 0x7F7F7F7Fu) & 0x80808080u;
                uint4 a4;
                a4.x = (f0 & 0x80u) * 0x7Fu + ((f0 >> 8) & 0x80u) * 0x7F0000u;   // 0x80*0x7F=0x3F80
                a4.y = ((f0 >> 16) & 0x80u) * 0x7Fu + (f0 >> 24) * 0x7F0000u;
                a4.z = (f1 & 0x80u) * 0x7Fu + ((f1 >> 8) & 0x80u) * 0x7F0000u;
                a4.w = ((f1 >> 16) & 0x80u) * 0x7Fu + (f1 >> 24) * 0x7F0000u;
                af[mt] = __builtin_bit_cast(bf16x8, a4);
            }
            bf16x8 bh[4], bl[4];
            #pragma unroll
            for (int nt = 0; nt < 4; ++nt) {
                const short* bp = Bh + (nt * 16 + l16) * BSTR + ks * 32 + quad * 8;
                bh[nt] = *(const bf16x8*)bp;
                bl[nt] = *(const bf16x8*)(bp + 64 * BSTR);
            }
            #pragma unroll
            for (int mt = 0; mt < 3; ++mt)
                #pragma unroll
                for (int nt = 0; nt < 4; ++nt)
                    acc[mt][nt] = __builtin_amdgcn_mfma_f32_16x16x32_bf16(af[mt], bh[nt], acc[mt][nt], 0, 0, 0);
            #pragma unroll
            for (int mt = 0; mt < 3; ++mt)
                #pragma unroll
                for (int nt = 0; nt < 4; ++nt)
                    acc[mt][nt] = __builtin_amdgcn_mfma_f32_16x16x32_bf16(af[mt], bl[nt], acc[mt][nt], 0, 0, 0);
        }
    }
    __syncthreads();   // last MFMA reads done before smem reuse

    // ---- epilogue: 3 phases of 5 p's (90 rows) through reused LDS ----
    const float ln18 = 2.8903717578961645f;
    const float inv_ln18 = 0.34598234401512115f;
    #pragma unroll 1
    for (int ph = 0; ph < 3; ++ph) {
        const int rlo = ph * 90, rhi = rlo + 90;
        // dump C fragments in range (C/D layout: col=lane&15, row=quad*4+reg)
        #pragma unroll
        for (int mt = 0; mt < 3; ++mt) {
            #pragma unroll
            for (int nt = 0; nt < 4; ++nt) {
                const int col = nt * 16 + l16;
                if (col <= FA) {
                    #pragma unroll
                    for (int r2 = 0; r2 < 4; ++r2) {
                        const int row = w * 48 + mt * 16 + quad * 4 + r2;
                        if (row >= rlo && row < rhi)
                            accs[(row - rlo) * ACCW + col] = acc[mt][nt][r2];
                    }
                }
            }
        }
        __syncthreads();
        if (tid < 5 * FA) {
            const int pidx = tid / FA;
            const int a = tid - pidx * FA;
            float means[NBINS];
            float tot = 0.f;
            #pragma unroll
            for (int k = 0; k < NBINS; ++k) {
                const float sum = accs[(pidx * NBINS + k) * ACCW + a];
                const float cnt = accs[(pidx * NBINS + k) * ACCW + FA];
                const float m = sum / (cnt + 1e-9f);
                means[k] = m;
                tot += m;
            }
            const float rden = 1.0f / (tot + 1e-9f);
            float ent = 0.f;
            #pragma unroll
            for (int k = 0; k < NBINS; ++k) {
                const float pr = means[k] * rden;
                ent += pr * logf(pr + 1e-9f);
            }
            const float mi = (ln18 + ent) * inv_ln18;
            const int p = ph * 5 + pidx;
            const int oi = (bc * FP + p0 + p) * FA + a;
            if (DIRECT) {
                atomicAdd(&outp[oi], mi * (1.0f / NS));
            } else {
                outp[(size_t)s * (NB * NC * FP * FA) + oi] = mi;   // s-major: kernel2 coalesced
            }
        }
        __syncthreads();
    }
}

__global__ void mi_reduce(const float* __restrict__ partial, float* __restrict__ out) {
    const int i = blockIdx.x * 256 + threadIdx.x;
    const int n = NB * NC * FP * FA;
    if (i < n) {
        float acc = 0.f;
        #pragma unroll
        for (int j = 0; j < NS; ++j) acc += partial[(size_t)j * n + i];
        out[i] = acc * (1.0f / NS);
    }
}

extern "C" void kernel_launch(void* const* d_in, const int* in_sizes, int n_in,
                              void* d_out, int out_size, void* d_ws, size_t ws_size,
                              hipStream_t stream) {
    const float* pha = (const float*)d_in[0];
    const float* amp = (const float*)d_in[1];
    const float* cut = (const float*)d_in[2];
    float* out = (float*)d_out;

    const int nout = NB * NC * FP * FA;                      // 48000
    const size_t need = (size_t)nout * NS * sizeof(float);   // 3.84 MB
    const dim3 grid(NB * NC * NS * 2);                       // 1280

    if (ws_size >= need) {
        float* partial = (float*)d_ws;
        mi_mfma<false><<<grid, NTHR, 0, stream>>>(pha, amp, cut, partial);
        mi_reduce<<<(nout + 255) / 256, 256, 0, stream>>>(partial, out);
    } else {
        hipMemsetAsync(d_out, 0, (size_t)nout * sizeof(float), stream);
        mi_mfma<true><<<grid, NTHR, 0, stream>>>(pha, amp, cut, out);
    }
}